// Round 10
// baseline (1128.886 us; speedup 1.0000x reference)
//
#include <hip/hip_runtime.h>
#include <hip/hip_bf16.h>
#include <math.h>

#define B 4096
#define S 32
#define D 256
#define V 50257
#define N_ALIVE 100
#define K_PAD 128          // K=100 zero-padded to 128 (4 x mfma K=32)
#define V_PAD 50432        // 197 * 256

typedef __attribute__((ext_vector_type(8))) short short8;   // 8 bf16 (4 VGPRs)
typedef __attribute__((ext_vector_type(4))) float float4v;  // 4 fp32 acc

__device__ __forceinline__ short f2bf(float f) {
    __hip_bfloat16 h = __float2bfloat16(f);
    return *reinterpret_cast<short*>(&h);
}

// ---------------------------------------------------------------------------
// Kernel A v2 (unchanged from R9): no embed LDS staging, ~2KB LDS.
// ---------------------------------------------------------------------------
__global__ __launch_bounds__(256) void ctx_act_kernel(
    const int*   __restrict__ token_ids,   // [B,S]
    const float* __restrict__ te,          // [V,D]
    const float* __restrict__ pe,          // [S,D]
    const float* __restrict__ q,           // [D]
    const float* __restrict__ pos,         // [N,D]
    __hip_bfloat16* __restrict__ A)        // [B, K_PAD]
{
    __shared__ int   s_ids[S];
    __shared__ float s_scores[S];
    __shared__ float s_w[S];
    __shared__ __align__(16) float s_ctx[D];
    __shared__ float s_red[128];
    __shared__ float s_total;

    const int b    = blockIdx.x;
    const int tid  = threadIdx.x;
    const int lane = tid & 63;
    const int wave = tid >> 6;

    if (tid < S) s_ids[tid] = token_ids[b * S + tid];
    __syncthreads();

    const float4 qv = *(const float4*)(q + lane * 4);
    #pragma unroll
    for (int j = 0; j < 8; ++j) {
        const int s = wave * 8 + j;
        const float4 t4 = *(const float4*)(te + (size_t)s_ids[s] * D + lane * 4);
        const float4 p4 = *(const float4*)(pe + (size_t)s * D + lane * 4);
        float p = (t4.x + p4.x) * qv.x + (t4.y + p4.y) * qv.y +
                  (t4.z + p4.z) * qv.z + (t4.w + p4.w) * qv.w;
        #pragma unroll
        for (int m = 32; m >= 1; m >>= 1) p += __shfl_xor(p, m);
        if (lane == 0) s_scores[s] = p * 0.0625f;   // 1/sqrt(256)
    }
    __syncthreads();

    if (tid < 32) {
        const float sc = s_scores[tid];
        float m = sc;
        #pragma unroll
        for (int k = 16; k >= 1; k >>= 1) m = fmaxf(m, __shfl_xor(m, k));
        const float e = expf(sc - m);
        float tot = e;
        #pragma unroll
        for (int k = 16; k >= 1; k >>= 1) tot += __shfl_xor(tot, k);
        s_w[tid] = e / tot;
    }
    __syncthreads();

    {
        float c = 0.f;
        #pragma unroll 8
        for (int s = 0; s < S; ++s) {
            const float ev = te[(size_t)s_ids[s] * D + tid] + pe[(size_t)s * D + tid];
            c = fmaf(s_w[s], ev, c);
        }
        s_ctx[tid] = c;
    }
    __syncthreads();

    float a = 0.f;
    if (tid < N_ALIVE) {
        const float4* p4 = (const float4*)(pos + (size_t)tid * D);
        const float4* c4 = (const float4*)s_ctx;
        float d2 = 0.f;
        #pragma unroll 8
        for (int dd = 0; dd < D / 4; ++dd) {
            const float4 cv = c4[dd];
            const float4 pv = p4[dd];
            const float dx = cv.x - pv.x;
            const float dy = cv.y - pv.y;
            const float dz = cv.z - pv.z;
            const float dw = cv.w - pv.w;
            d2 += dx * dx + dy * dy + dz * dz + dw * dw;
        }
        a = expf(-2.0f * d2);   // exp(-d2 / (2 * 0.5^2))
    }
    if (tid < 128) s_red[tid] = (tid < N_ALIVE) ? a : 0.f;
    __syncthreads();
    if (tid < 64) s_red[tid] += s_red[tid + 64];
    __syncthreads();
    if (tid < 64) {
        float v = s_red[tid];
        #pragma unroll
        for (int k = 32; k >= 1; k >>= 1) v += __shfl_xor(v, k);
        if (tid == 0) s_total = v;
    }
    __syncthreads();
    if (tid < K_PAD) {
        const float val = (tid < N_ALIVE) ? (a / (s_total + 1e-8f)) : 0.f;
        A[(size_t)b * K_PAD + tid] = __float2bfloat16(val);
    }
}

// ---------------------------------------------------------------------------
// Transpose/convert: Wt[v][k] = bf16(W[k][v]), zero-padded.  (unchanged)
// ---------------------------------------------------------------------------
__global__ __launch_bounds__(256) void transpose_w(
    const float* __restrict__ W,            // [N_ALIVE, V]
    __hip_bfloat16* __restrict__ Wt)        // [V_PAD, K_PAD]
{
    const int v  = blockIdx.x * 256 + threadIdx.x;
    const int k0 = blockIdx.y * 16;
    short8 p0, p1;
    #pragma unroll
    for (int kk = 0; kk < 8; ++kk) {
        const int k = k0 + kk;
        p0[kk] = f2bf((v < V && k < N_ALIVE) ? W[(size_t)k * V + v] : 0.f);
    }
    #pragma unroll
    for (int kk = 0; kk < 8; ++kk) {
        const int k = k0 + 8 + kk;
        p1[kk] = f2bf((v < V && k < N_ALIVE) ? W[(size_t)k * V + v] : 0.f);
    }
    short* dst = (short*)Wt + (size_t)v * K_PAD + k0;
    *(short8*)dst       = p0;
    *(short8*)(dst + 8) = p1;
}

// ---------------------------------------------------------------------------
// Kernel B v8: block-level epilogue with FULL-ROW 1KB store instructions.
// Model (fits R1/R3/R4/R6/R7): L2 write-combining is per-instruction;
// chunks >=64B are sector-clean, but misaligned 256B chunks still leave
// 2/3 of touched lines partial -> HBM RMW at chunk edges.  R1's 1KB-per-
// instruction chunks (2/9 partial) measured clean.  So: stage each n-tile's
// 16 rows x 256 v in block LDS, sync, then each wave stores 4 ENTIRE rows
// (one 1KB dwordx4 instruction per row).  K-loop unchanged (NT=8).
//   A-op = Wt row (m=v): m=lane&15, k=quad*8+j
//   B-op = act row (n=b): n=lane&15, k=quad*8+j
//   C/D: col(=b)=lane&15, row(=v)=quad*4+reg
// ---------------------------------------------------------------------------
#define EP_LD 260   // floats per staged row (256 + 4 pad)
#define NT 8        // 8 n-tiles of 16 b-rows = 128 batch rows per block

__global__ __launch_bounds__(256) void gemm_mfma(
    const __hip_bfloat16* __restrict__ Act,  // [B, K_PAD]
    const __hip_bfloat16* __restrict__ Wt,   // [V_PAD, K_PAD]
    float* __restrict__ out)                 // [B, V]
{
    __shared__ __align__(16) float s_ep[16 * EP_LD];   // 16640 B

    const int tid  = threadIdx.x;
    const int lane = tid & 63;
    const int wave = tid >> 6;
    const int quad = lane >> 4;
    const int l16  = lane & 15;
    const int b0   = blockIdx.y * (NT * 16);   // 128 batch rows per block
    const int x0   = blockIdx.x * 256;
    const int wx0  = x0 + wave * 64;           // this wave's 64 v-cols

    const short* wtbase = (const short*)Wt + (size_t)(wx0 + l16) * K_PAD + quad * 8;

    #pragma unroll
    for (int n = 0; n < NT; ++n) {
        // act fragments for this n-tile (b = b0 + n*16 + l16)
        const short* actp = (const short*)Act +
                            (size_t)(b0 + n * 16 + l16) * K_PAD + quad * 8;
        short8 bf[4];
        #pragma unroll
        for (int ks = 0; ks < 4; ++ks) bf[ks] = *(const short8*)(actp + ks * 32);

        #pragma unroll
        for (int mt = 0; mt < 4; ++mt) {
            const short* ap = wtbase + (size_t)(mt * 16) * K_PAD;
            float4v acc = {0.f, 0.f, 0.f, 0.f};
            #pragma unroll
            for (int ks = 0; ks < 4; ++ks) {
                const short8 af = *(const short8*)(ap + ks * 32);
                acc = __builtin_amdgcn_mfma_f32_16x16x32_bf16(af, bf[ks], acc, 0, 0, 0);
            }
            // stage: row = b_local = l16, col (within block) = wave*64 + mt*16 + quad*4
            *(float4v*)(s_ep + l16 * EP_LD + wave * 64 + mt * 16 + quad * 4) = acc;
        }

        __syncthreads();   // all strips staged

        // each wave stores 4 entire rows; one 1KB instruction per row
        #pragma unroll
        for (int p = 0; p < 4; ++p) {
            const int row   = wave * 4 + p;             // 0..15 (b_local)
            const int vglob = x0 + lane * 4;
            const float4 val = *(const float4*)(s_ep + row * EP_LD + lane * 4);
            float* orow = out + (size_t)(b0 + n * 16 + row) * V + vglob;
            if (vglob + 4 <= V) {
                *(float4*)orow = val;
            } else {
                if (vglob + 0 < V) orow[0] = val.x;
                if (vglob + 1 < V) orow[1] = val.y;
                if (vglob + 2 < V) orow[2] = val.z;
                if (vglob + 3 < V) orow[3] = val.w;
            }
        }

        __syncthreads();   // buffer reuse guard for next n-tile
    }
}

// ---------------------------------------------------------------------------
// Fallback (ws too small for Wt): fp32 VALU, TB=16 rows in VGPRs.
// ---------------------------------------------------------------------------
__global__ __launch_bounds__(256) void logits_fallback(
    const __hip_bfloat16* __restrict__ A,   // [B, K_PAD]
    const float* __restrict__ W,            // [N_ALIVE, V]
    float* __restrict__ out)                // [B, V]
{
    const int v  = blockIdx.x * 256 + threadIdx.x;
    const int b0 = blockIdx.y * 16;
    const bool valid = (v < V);

    float acc[16];
    #pragma unroll
    for (int i = 0; i < 16; ++i) acc[i] = 0.f;

    for (int k = 0; k < N_ALIVE; ++k) {
        const float w = valid ? W[(size_t)k * V + v] : 0.f;
        #pragma unroll
        for (int i = 0; i < 16; ++i) {
            const float a = __bfloat162float(A[(size_t)(b0 + i) * K_PAD + k]);
            acc[i] = fmaf(a, w, acc[i]);
        }
    }
    if (valid) {
        #pragma unroll
        for (int i = 0; i < 16; ++i)
            out[(size_t)(b0 + i) * V + v] = acc[i];
    }
}

// ---------------------------------------------------------------------------
extern "C" void kernel_launch(void* const* d_in, const int* in_sizes, int n_in,
                              void* d_out, int out_size, void* d_ws, size_t ws_size,
                              hipStream_t stream) {
    const int*   token_ids = (const int*)d_in[0];
    const float* te        = (const float*)d_in[1];
    const float* pe        = (const float*)d_in[2];
    const float* q         = (const float*)d_in[3];
    const float* pos       = (const float*)d_in[4];
    const float* W         = (const float*)d_in[5];
    float*       out       = (float*)d_out;

    __hip_bfloat16* Abf = (__hip_bfloat16*)d_ws;                  // 1 MiB
    const size_t offW   = (size_t)B * K_PAD * sizeof(__hip_bfloat16);
    __hip_bfloat16* Wt  = (__hip_bfloat16*)((char*)d_ws + offW);  // ~12.9 MB
    const size_t need   = offW + (size_t)V_PAD * K_PAD * sizeof(__hip_bfloat16);

    ctx_act_kernel<<<dim3(B), dim3(256), 0, stream>>>(token_ids, te, pe, q, pos, Abf);

    if (ws_size >= need) {
        transpose_w<<<dim3(V_PAD / 256, 8), dim3(256), 0, stream>>>(W, Wt);
        gemm_mfma<<<dim3(V_PAD / 256, B / (NT * 16)), dim3(256), 0, stream>>>(Abf, Wt, out);
    } else {
        logits_fallback<<<dim3((V + 255) / 256, B / 16), dim3(256), 0, stream>>>(Abf, W, out);
    }
}

// Round 11
// 1101.973 us; speedup vs baseline: 1.0244x; 1.0244x over previous
//
#include <hip/hip_runtime.h>
#include <hip/hip_bf16.h>
#include <math.h>

#define B 4096
#define S 32
#define D 256
#define V 50257
#define N_ALIVE 100
#define K_PAD 128          // K=100 zero-padded to 128 (4 x mfma K=32)
#define V_PAD 50432        // 197 * 256

typedef __attribute__((ext_vector_type(8))) short short8;   // 8 bf16 (4 VGPRs)
typedef __attribute__((ext_vector_type(4))) float float4v;  // 4 fp32 acc

__device__ __forceinline__ short f2bf(float f) {
    __hip_bfloat16 h = __float2bfloat16(f);
    return *reinterpret_cast<short*>(&h);
}

// ---------------------------------------------------------------------------
// Kernel A v3: single te pass, embeds kept in REGISTERS.
// R10 post-mortem: ctx ~190us was latency on the context phase's 32 serial
// L3 re-reads (R9) or 32KB LDS occupancy loss (R2).  Now: score phase keeps
// its 8 rows x float4/lane in regs (32 VGPR); context phase is pure register
// FMA producing per-wave partials; 4KB LDS cross-wave reduce.  One te pass,
// zero context-phase loads, ~5.5KB LDS.
// ---------------------------------------------------------------------------
__global__ __launch_bounds__(256) void ctx_act_kernel(
    const int*   __restrict__ token_ids,   // [B,S]
    const float* __restrict__ te,          // [V,D]
    const float* __restrict__ pe,          // [S,D]
    const float* __restrict__ q,           // [D]
    const float* __restrict__ pos,         // [N,D]
    __hip_bfloat16* __restrict__ A)        // [B, K_PAD]
{
    __shared__ int   s_ids[S];
    __shared__ float s_scores[S];
    __shared__ float s_w[S];
    __shared__ __align__(16) float s_part[4][D];   // 4 KB per-wave partials
    __shared__ __align__(16) float s_ctx[D];
    __shared__ float s_red[128];
    __shared__ float s_total;

    const int b    = blockIdx.x;
    const int tid  = threadIdx.x;
    const int lane = tid & 63;
    const int wave = tid >> 6;

    if (tid < S) s_ids[tid] = token_ids[b * S + tid];
    __syncthreads();

    // ---- phase 1: load embeds (kept in regs) + attention scores ----
    const float4 qv = *(const float4*)(q + lane * 4);
    float4 e4[8];
    #pragma unroll
    for (int j = 0; j < 8; ++j) {
        const int s = wave * 8 + j;
        const float4 t4 = *(const float4*)(te + (size_t)s_ids[s] * D + lane * 4);
        const float4 p4 = *(const float4*)(pe + (size_t)s * D + lane * 4);
        e4[j].x = t4.x + p4.x; e4[j].y = t4.y + p4.y;
        e4[j].z = t4.z + p4.z; e4[j].w = t4.w + p4.w;
        float p = e4[j].x * qv.x + e4[j].y * qv.y + e4[j].z * qv.z + e4[j].w * qv.w;
        #pragma unroll
        for (int m = 32; m >= 1; m >>= 1) p += __shfl_xor(p, m);
        if (lane == 0) s_scores[s] = p * 0.0625f;   // 1/sqrt(256)
    }
    __syncthreads();

    // ---- phase 2: softmax over S=32 (first 32 lanes of wave 0) ----
    if (tid < 32) {
        const float sc = s_scores[tid];
        float m = sc;
        #pragma unroll
        for (int k = 16; k >= 1; k >>= 1) m = fmaxf(m, __shfl_xor(m, k));
        const float e = expf(sc - m);
        float tot = e;
        #pragma unroll
        for (int k = 16; k >= 1; k >>= 1) tot += __shfl_xor(tot, k);
        s_w[tid] = e / tot;
    }
    __syncthreads();

    // ---- phase 3: per-wave partial context, pure register FMA ----
    {
        float4 c4 = {0.f, 0.f, 0.f, 0.f};
        #pragma unroll
        for (int j = 0; j < 8; ++j) {
            const float w = s_w[wave * 8 + j];
            c4.x = fmaf(w, e4[j].x, c4.x);
            c4.y = fmaf(w, e4[j].y, c4.y);
            c4.z = fmaf(w, e4[j].z, c4.z);
            c4.w = fmaf(w, e4[j].w, c4.w);
        }
        *(float4*)&s_part[wave][lane * 4] = c4;
    }
    __syncthreads();

    // ---- phase 4: cross-wave reduce -> s_ctx (thread owns d = tid) ----
    s_ctx[tid] = s_part[0][tid] + s_part[1][tid] + s_part[2][tid] + s_part[3][tid];
    __syncthreads();

    // ---- phase 5: RBF activations: thread n = tid (n < 100) ----
    float a = 0.f;
    if (tid < N_ALIVE) {
        const float4* p4 = (const float4*)(pos + (size_t)tid * D);
        const float4* c4 = (const float4*)s_ctx;
        float d2 = 0.f;
        #pragma unroll 8
        for (int dd = 0; dd < D / 4; ++dd) {
            const float4 cv = c4[dd];
            const float4 pv = p4[dd];
            const float dx = cv.x - pv.x;
            const float dy = cv.y - pv.y;
            const float dz = cv.z - pv.z;
            const float dw = cv.w - pv.w;
            d2 += dx * dx + dy * dy + dz * dz + dw * dw;
        }
        a = expf(-2.0f * d2);   // exp(-d2 / (2 * 0.5^2))
    }
    if (tid < 128) s_red[tid] = (tid < N_ALIVE) ? a : 0.f;
    __syncthreads();
    if (tid < 64) s_red[tid] += s_red[tid + 64];
    __syncthreads();
    if (tid < 64) {
        float v = s_red[tid];
        #pragma unroll
        for (int k = 32; k >= 1; k >>= 1) v += __shfl_xor(v, k);
        if (tid == 0) s_total = v;
    }
    __syncthreads();
    if (tid < K_PAD) {
        const float val = (tid < N_ALIVE) ? (a / (s_total + 1e-8f)) : 0.f;
        A[(size_t)b * K_PAD + tid] = __float2bfloat16(val);
    }
}

// ---------------------------------------------------------------------------
// Transpose/convert: Wt[v][k] = bf16(W[k][v]), zero-padded.  (unchanged)
// ---------------------------------------------------------------------------
__global__ __launch_bounds__(256) void transpose_w(
    const float* __restrict__ W,            // [N_ALIVE, V]
    __hip_bfloat16* __restrict__ Wt)        // [V_PAD, K_PAD]
{
    const int v  = blockIdx.x * 256 + threadIdx.x;
    const int k0 = blockIdx.y * 16;
    short8 p0, p1;
    #pragma unroll
    for (int kk = 0; kk < 8; ++kk) {
        const int k = k0 + kk;
        p0[kk] = f2bf((v < V && k < N_ALIVE) ? W[(size_t)k * V + v] : 0.f);
    }
    #pragma unroll
    for (int kk = 0; kk < 8; ++kk) {
        const int k = k0 + 8 + kk;
        p1[kk] = f2bf((v < V && k < N_ALIVE) ? W[(size_t)k * V + v] : 0.f);
    }
    short* dst = (short*)Wt + (size_t)v * K_PAD + k0;
    *(short8*)dst       = p0;
    *(short8*)(dst + 8) = p1;
}

// ---------------------------------------------------------------------------
// Kernel B: EXACT R9 gemm (best measured config: total 1109).
// Wave-private 256B-chunk epilogue, NT=8 y-widened blocks, Wt frags hoisted.
//   A-op = Wt row (m=v): m=lane&15, k=quad*8+j
//   B-op = act row (n=b): n=lane&15, k=quad*8+j
//   C/D: col(=b)=lane&15, row(=v)=quad*4+reg
// ---------------------------------------------------------------------------
#define EPS_LD 68   // floats per staged row (64 + 4 pad), 16B-aligned
#define NT 8        // 8 n-tiles of 16 b-rows = 128 batch rows per block

__global__ __launch_bounds__(256) void gemm_mfma(
    const __hip_bfloat16* __restrict__ Act,  // [B, K_PAD]
    const __hip_bfloat16* __restrict__ Wt,   // [V_PAD, K_PAD]
    float* __restrict__ out)                 // [B, V]
{
    __shared__ __align__(16) float s_c[4][16 * EPS_LD];   // 17408 B, per-wave

    const int tid  = threadIdx.x;
    const int lane = tid & 63;
    const int wave = tid >> 6;
    const int quad = lane >> 4;
    const int l16  = lane & 15;
    const int b0   = blockIdx.y * (NT * 16);   // 128 batch rows per block
    const int x0   = blockIdx.x * 256;
    const int wx0  = x0 + wave * 64;           // this wave's 64 v-cols

    float* buf = s_c[wave];

    // ---- hoist Wt fragments for all 4 m-tiles (block lifetime, 64 VGPR) ----
    const short* wtbase = (const short*)Wt + (size_t)(wx0 + l16) * K_PAD + quad * 8;
    short8 wf[4][4];
    #pragma unroll
    for (int mt = 0; mt < 4; ++mt) {
        const short* ap = wtbase + (size_t)(mt * 16) * K_PAD;
        #pragma unroll
        for (int ks = 0; ks < 4; ++ks) wf[mt][ks] = *(const short8*)(ap + ks * 32);
    }

    #pragma unroll
    for (int n = 0; n < NT; ++n) {
        const short* actp = (const short*)Act +
                            (size_t)(b0 + n * 16 + l16) * K_PAD + quad * 8;
        short8 bf[4];
        #pragma unroll
        for (int ks = 0; ks < 4; ++ks) bf[ks] = *(const short8*)(actp + ks * 32);

        #pragma unroll
        for (int mt = 0; mt < 4; ++mt) {
            float4v acc = {0.f, 0.f, 0.f, 0.f};
            #pragma unroll
            for (int ks = 0; ks < 4; ++ks)
                acc = __builtin_amdgcn_mfma_f32_16x16x32_bf16(wf[mt][ks], bf[ks], acc, 0, 0, 0);
            *(float4v*)(buf + l16 * EPS_LD + mt * 16 + quad * 4) = acc;
        }

        __builtin_amdgcn_wave_barrier();   // order LDS write->read (same wave)

        #pragma unroll
        for (int p = 0; p < 4; ++p) {
            const int row  = p * 4 + quad;         // 0..15  (b_local)
            const int vloc = l16 * 4;              // 0..60
            const float4 val = *(const float4*)(buf + row * EPS_LD + vloc);
            const int vglob = wx0 + vloc;
            float* orow = out + (size_t)(b0 + n * 16 + row) * V + vglob;
            if (vglob + 4 <= V) {
                *(float4*)orow = val;
            } else {
                if (vglob + 0 < V) orow[0] = val.x;
                if (vglob + 1 < V) orow[1] = val.y;
                if (vglob + 2 < V) orow[2] = val.z;
                if (vglob + 3 < V) orow[3] = val.w;
            }
        }

        __builtin_amdgcn_wave_barrier();   // buffer reuse guard
    }
}

// ---------------------------------------------------------------------------
// Fallback (ws too small for Wt): fp32 VALU, TB=16 rows in VGPRs.
// ---------------------------------------------------------------------------
__global__ __launch_bounds__(256) void logits_fallback(
    const __hip_bfloat16* __restrict__ A,   // [B, K_PAD]
    const float* __restrict__ W,            // [N_ALIVE, V]
    float* __restrict__ out)                // [B, V]
{
    const int v  = blockIdx.x * 256 + threadIdx.x;
    const int b0 = blockIdx.y * 16;
    const bool valid = (v < V);

    float acc[16];
    #pragma unroll
    for (int i = 0; i < 16; ++i) acc[i] = 0.f;

    for (int k = 0; k < N_ALIVE; ++k) {
        const float w = valid ? W[(size_t)k * V + v] : 0.f;
        #pragma unroll
        for (int i = 0; i < 16; ++i) {
            const float a = __bfloat162float(A[(size_t)(b0 + i) * K_PAD + k]);
            acc[i] = fmaf(a, w, acc[i]);
        }
    }
    if (valid) {
        #pragma unroll
        for (int i = 0; i < 16; ++i)
            out[(size_t)(b0 + i) * V + v] = acc[i];
    }
}

// ---------------------------------------------------------------------------
extern "C" void kernel_launch(void* const* d_in, const int* in_sizes, int n_in,
                              void* d_out, int out_size, void* d_ws, size_t ws_size,
                              hipStream_t stream) {
    const int*   token_ids = (const int*)d_in[0];
    const float* te        = (const float*)d_in[1];
    const float* pe        = (const float*)d_in[2];
    const float* q         = (const float*)d_in[3];
    const float* pos       = (const float*)d_in[4];
    const float* W         = (const float*)d_in[5];
    float*       out       = (float*)d_out;

    __hip_bfloat16* Abf = (__hip_bfloat16*)d_ws;                  // 1 MiB
    const size_t offW   = (size_t)B * K_PAD * sizeof(__hip_bfloat16);
    __hip_bfloat16* Wt  = (__hip_bfloat16*)((char*)d_ws + offW);  // ~12.9 MB
    const size_t need   = offW + (size_t)V_PAD * K_PAD * sizeof(__hip_bfloat16);

    ctx_act_kernel<<<dim3(B), dim3(256), 0, stream>>>(token_ids, te, pe, q, pos, Abf);

    if (ws_size >= need) {
        transpose_w<<<dim3(V_PAD / 256, 8), dim3(256), 0, stream>>>(W, Wt);
        gemm_mfma<<<dim3(V_PAD / 256, B / (NT * 16)), dim3(256), 0, stream>>>(Abf, Wt, out);
    } else {
        logits_fallback<<<dim3((V + 255) / 256, B / 16), dim3(256), 0, stream>>>(Abf, W, out);
    }
}